// Round 2
// baseline (312.497 us; speedup 1.0000x reference)
//
#include <hip/hip_runtime.h>
#include <hip/hip_bf16.h>
#include <stdint.h>

#define N_ROWS 4096
#define H_DIM  1024
#define V_SIZE 32000
#define IGNORE_INDEX (-100)

#define BM 256                  // vocab tile
#define BN 256                  // row tile
#define BK 32                   // K tile
#define KT (H_DIM / BK)         // 32 K-tiles
#define VT_N (V_SIZE / BM)      // 125
#define NT_N (N_ROWS / BN)      // 16
#define NWG  (VT_N * NT_N)      // 2000 (% 8 == 0 -> simple XCD swizzle valid)
#define BUFB  32768             // bytes per K-tile buffer (A 16K + B 16K)
#define BPART 16384
#define LDS_BYTES 131072        // 4 buffers

typedef short short8 __attribute__((ext_vector_type(8)));
typedef float floatx4 __attribute__((ext_vector_type(4)));

static __device__ __forceinline__ unsigned short f2bf(float f) {
    uint32_t u = __float_as_uint(f);
    uint32_t r = (u + 0x7fffu + ((u >> 16) & 1u)) >> 16;
    return (unsigned short)r;
}
static __device__ __forceinline__ float bf2f(unsigned short b) {
    return __uint_as_float(((uint32_t)b) << 16);
}

static __device__ __forceinline__ void gload_lds16(const void* g, void* l) {
    __builtin_amdgcn_global_load_lds(
        (const __attribute__((address_space(1))) unsigned int*)g,
        (__attribute__((address_space(3))) unsigned int*)l,
        16, 0, 0);
}

// ---- K1: x fp32 -> bf16 ----------------------------------------------------
__global__ void k_convert_x(const float* __restrict__ x, unsigned short* __restrict__ xb) {
    int i = (blockIdx.x * blockDim.x + threadIdx.x) * 4;
    float4 v = *(const float4*)(x + i);
    ushort4 o;
    o.x = f2bf(v.x); o.y = f2bf(v.y); o.z = f2bf(v.z); o.w = f2bf(v.w);
    *(ushort4*)(xb + i) = o;
}

// ---- K2: W [H][V] fp32 -> Wt [V][H] bf16 (tiled transpose) -----------------
__global__ void k_transpose_w(const float* __restrict__ W, unsigned short* __restrict__ wt) {
    __shared__ unsigned short tile[32][33];
    int v0 = blockIdx.x * 32;
    int k0 = blockIdx.y * 32;
    int tx = threadIdx.x;   // 0..31
    int ty = threadIdx.y;   // 0..7
#pragma unroll
    for (int i = 0; i < 4; ++i) {
        int k = k0 + ty + i * 8;
        tile[ty + i * 8][tx] = f2bf(W[(size_t)k * V_SIZE + v0 + tx]);
    }
    __syncthreads();
#pragma unroll
    for (int i = 0; i < 4; ++i) {
        int v = v0 + ty + i * 8;
        wt[(size_t)v * H_DIM + k0 + tx] = tile[tx][ty + i * 8];
    }
}

// ---- K3: 256x256 quad-buffered deep-pipelined GEMM + exp-sum epilogue ------
// D[v][n] = sum_k Wt[v][k]*xb[n][k]; Spart[vt][n] = sum_{v in tile} exp(D)
// 8 waves (2 M x 4 N), per-wave 128x64 output, 16x16x32 bf16 MFMA.
// Quad-buffer: tile t reads buf[t&3]; stages for t+2 target buf[(t+2)&3],
// untouched since tile t-2 -> no write-while-read race by construction.
// Tile-end wait = counted vmcnt(4) (t+2's 4 loads stay in flight).
extern "C" __global__ __launch_bounds__(512, 2) void k_gemm_expsum(
    const unsigned short* __restrict__ wt,
    const unsigned short* __restrict__ xb,
    float* __restrict__ Spart)
{
    extern __shared__ char smem[];

    const int bid = blockIdx.x;
    const int wgid = (bid & 7) * (NWG / 8) + (bid >> 3);   // XCD-aware swizzle
    const int vt = wgid >> 4;
    const int nt = wgid & 15;

    const int t0 = threadIdx.x;
    const int lane = t0 & 63;
    const int w = t0 >> 6;      // wave 0..7
    const int wr = w >> 2;      // M half
    const int wc = w & 3;       // N quarter

    const char* aG = (const char*)wt + (size_t)vt * BM * (H_DIM * 2);
    const char* bG = (const char*)xb + (size_t)nt * BN * (H_DIM * 2);

    // stage: LDS linear (row, seg) holds global (row, seg ^ m(row)),
    // m(row) = (row&3)^((row>>2)&3); per-lane: row = chunk*16 + (l>>2), seg = l&3
    const int srcseg16 = (((lane & 3) ^ ((lane >> 2) & 3) ^ ((lane >> 4) & 3)) << 4);
    const int rowl2048 = (lane >> 2) * (H_DIM * 2);
    // read: slot = kseg ^ m(row); row = base + (lane&15), kseg = lane>>4
    const int rdswz = (((lane >> 4) ^ (lane & 3) ^ ((lane >> 2) & 3)) << 4);
    const int arow = (wr * 128 + (lane & 15)) * 64 + rdswz;
    const int brow = BPART + (wc * 64 + (lane & 15)) * 64 + rdswz;

    floatx4 acc[8][4] = {};

#define STAGE_A(s) do { \
        char* lp_ = smem + ((s) & 3) * BUFB; \
        _Pragma("unroll") \
        for (int c_ = 0; c_ < 2; ++c_) \
            gload_lds16(aG + (size_t)((c_ * 8 + w) * 16) * (H_DIM * 2) + rowl2048 \
                            + (s) * (BK * 2) + srcseg16, \
                        lp_ + (c_ * 8 + w) * 1024); \
    } while (0)
#define STAGE_B(s) do { \
        char* lp_ = smem + ((s) & 3) * BUFB + BPART; \
        _Pragma("unroll") \
        for (int c_ = 0; c_ < 2; ++c_) \
            gload_lds16(bG + (size_t)((c_ * 8 + w) * 16) * (H_DIM * 2) + rowl2048 \
                            + (s) * (BK * 2) + srcseg16, \
                        lp_ + (c_ * 8 + w) * 1024); \
    } while (0)

    // prologue: tiles 0 and 1 in flight; wait tile 0 (leave tile 1's 4 loads out)
    STAGE_A(0); STAGE_B(0);
    STAGE_A(1); STAGE_B(1);
    asm volatile("s_waitcnt vmcnt(4)" ::: "memory");
    __builtin_amdgcn_s_barrier();

#pragma unroll 1
    for (int t = 0; t < KT; ++t) {
        const char* buf = smem + (t & 3) * BUFB;
        short8 bf[4], af[4];
        // ---- phase 1: B frags + A frags m0..3, stage A(t+2) ----
#pragma unroll
        for (int n = 0; n < 4; ++n)
            bf[n] = *(const short8*)(buf + brow + n * 1024);
#pragma unroll
        for (int m = 0; m < 4; ++m)
            af[m] = *(const short8*)(buf + arow + m * 1024);
        if (t < KT - 2) STAGE_A(t + 2);
        asm volatile("" ::: "memory");
        __builtin_amdgcn_s_barrier();
        __builtin_amdgcn_s_setprio(1);
#pragma unroll
        for (int m = 0; m < 4; ++m)
#pragma unroll
            for (int n = 0; n < 4; ++n)
                acc[m][n] = __builtin_amdgcn_mfma_f32_16x16x32_bf16(af[m], bf[n], acc[m][n], 0, 0, 0);
        __builtin_amdgcn_s_setprio(0);
        // ---- phase 2: A frags m4..7, stage B(t+2) ----
#pragma unroll
        for (int m = 0; m < 4; ++m)
            af[m] = *(const short8*)(buf + arow + (m + 4) * 1024);
        if (t < KT - 2) STAGE_B(t + 2);
        asm volatile("" ::: "memory");
        __builtin_amdgcn_s_barrier();
        __builtin_amdgcn_s_setprio(1);
#pragma unroll
        for (int m = 0; m < 4; ++m)
#pragma unroll
            for (int n = 0; n < 4; ++n)
                acc[m + 4][n] = __builtin_amdgcn_mfma_f32_16x16x32_bf16(af[m], bf[n], acc[m + 4][n], 0, 0, 0);
        __builtin_amdgcn_s_setprio(0);
        // ---- tile end: counted wait (never 0 until drain) ----
        if (t < KT - 2)       { asm volatile("s_waitcnt vmcnt(4)" ::: "memory"); }
        else if (t == KT - 2) { asm volatile("s_waitcnt vmcnt(0)" ::: "memory"); }
        __builtin_amdgcn_s_barrier();
    }
#undef STAGE_A
#undef STAGE_B

    // epilogue: exp + column sums. C/D map: col = lane&15 (n), row = (lane>>4)*4+r (v)
    float csum[4];
#pragma unroll
    for (int n = 0; n < 4; ++n) {
        float s = 0.f;
#pragma unroll
        for (int m = 0; m < 8; ++m)
#pragma unroll
            for (int r = 0; r < 4; ++r)
                s += __expf(acc[m][n][r]);
        s += __shfl_xor(s, 16, 64);
        s += __shfl_xor(s, 32, 64);
        csum[n] = s;
    }
    __syncthreads();
    float* red = (float*)smem;
    if (lane < 16) {
#pragma unroll
        for (int n = 0; n < 4; ++n)
            red[wr * 256 + wc * 64 + n * 16 + lane] = csum[n];
    }
    __syncthreads();
    if (t0 < BN)
        Spart[(size_t)vt * N_ROWS + nt * BN + t0] = red[t0] + red[256 + t0];
}

// ---- K4: target logits (bf16 dot, consistent with GEMM inputs) -------------
__global__ void k_tgt(const unsigned short* __restrict__ xb,
                      const unsigned short* __restrict__ wt,
                      const int* __restrict__ tgt,
                      float* __restrict__ tlog)
{
    int w = threadIdx.x >> 6;
    int lane = threadIdx.x & 63;
    int n = blockIdx.x * 4 + w;
    int tg = tgt[n];
    int ts = (tg == IGNORE_INDEX) ? 0 : tg;
    const unsigned short* xr = xb + (size_t)n * H_DIM;
    const unsigned short* wr = wt + (size_t)ts * H_DIM;
    float s = 0.f;
#pragma unroll
    for (int i = 0; i < H_DIM / 64; ++i) {
        int k = lane + i * 64;
        s += bf2f(xr[k]) * bf2f(wr[k]);
    }
#pragma unroll
    for (int off = 32; off; off >>= 1) s += __shfl_xor(s, off, 64);
    if (lane == 0) tlog[n] = s;
}

// ---- K5: per-row loss + block partials -------------------------------------
__global__ void k_rowloss(const float* __restrict__ Spart,
                          const float* __restrict__ tlog,
                          const int* __restrict__ tgt,
                          float* __restrict__ partials)
{
    int n = blockIdx.x * 256 + threadIdx.x;
    float S = 0.f;
    for (int vt2 = 0; vt2 < VT_N; ++vt2)
        S += Spart[(size_t)vt2 * N_ROWS + n];
    float loss = 0.f;
    int tg = tgt[n];
    if (tg != IGNORE_INDEX) loss = logf(S) - tlog[n];

    __shared__ float sm[256];
    sm[threadIdx.x] = loss;
    __syncthreads();
    for (int s2 = 128; s2 > 0; s2 >>= 1) {
        if (threadIdx.x < s2) sm[threadIdx.x] += sm[threadIdx.x + s2];
        __syncthreads();
    }
    if (threadIdx.x == 0) partials[blockIdx.x] = sm[0];
}

__global__ void k_final(const float* __restrict__ partials, float* __restrict__ out) {
    if (threadIdx.x == 0) {
        float s = 0.f;
        for (int i = 0; i < 16; ++i) s += partials[i];
        out[0] = s;
    }
}

// ---- launch ----------------------------------------------------------------
extern "C" void kernel_launch(void* const* d_in, const int* in_sizes, int n_in,
                              void* d_out, int out_size, void* d_ws, size_t ws_size,
                              hipStream_t stream)
{
    const float* x = (const float*)d_in[0];
    const float* W = (const float*)d_in[1];
    const int* tgt = (const int*)d_in[2];
    float* out = (float*)d_out;

    char* ws = (char*)d_ws;
    size_t off = 0;
    unsigned short* xb = (unsigned short*)(ws + off); off += (size_t)N_ROWS * H_DIM * 2;
    unsigned short* wt = (unsigned short*)(ws + off); off += (size_t)V_SIZE * H_DIM * 2;
    float* Spart = (float*)(ws + off);                off += (size_t)VT_N * N_ROWS * 4;
    float* tlog  = (float*)(ws + off);                off += (size_t)N_ROWS * 4;
    float* partials = (float*)(ws + off);             off += 64;

    hipFuncSetAttribute((const void*)k_gemm_expsum,
                        hipFuncAttributeMaxDynamicSharedMemorySize, LDS_BYTES);

    k_convert_x<<<(N_ROWS * H_DIM / 4) / 256, 256, 0, stream>>>(x, xb);
    k_transpose_w<<<dim3(V_SIZE / 32, H_DIM / 32), dim3(32, 8), 0, stream>>>(W, wt);
    k_gemm_expsum<<<NWG, 512, LDS_BYTES, stream>>>(wt, xb, Spart);
    k_tgt<<<N_ROWS / 4, 256, 0, stream>>>(xb, wt, tgt, tlog);
    k_rowloss<<<16, 256, 0, stream>>>(Spart, tlog, tgt, partials);
    k_final<<<1, 64, 0, stream>>>(partials, out);
}

// Round 3
// 186.414 us; speedup vs baseline: 1.6764x; 1.6764x over previous
//
#include <hip/hip_runtime.h>
#include <hip/hip_bf16.h>
#include <stdint.h>

#define N_ROWS 4096
#define H_DIM  1024
#define V_SIZE 32000
#define IGNORE_INDEX (-100)

#define BV 128   // vocab tile (MFMA M dim)
#define BN 128   // row tile   (MFMA N dim)
#define BKB 128  // K-tile bytes = 128 i8 elements
#define N_TILES (N_ROWS / BN)   // 32
#define V_TILES (V_SIZE / BV)   // 250
#define K_TILES (H_DIM / BKB)   // 8

#define XSCALE 16.0f
#define WSCALE 512.0f
#define DESCALE (1.0f / (16.0f * 512.0f))

typedef int intx4 __attribute__((ext_vector_type(4)));

static __device__ __forceinline__ int q8(float f, float s) {
    int r = __float2int_rn(f * s);
    r = r > 127 ? 127 : (r < -127 ? -127 : r);
    return r & 0xff;
}

static __device__ __forceinline__ void gload_lds16(const void* g, void* l) {
    __builtin_amdgcn_global_load_lds(
        (const __attribute__((address_space(1))) unsigned int*)g,
        (__attribute__((address_space(3))) unsigned int*)l,
        16, 0, 0);
}

// ---- K1: x fp32 -> i8 (scale 16) -------------------------------------------
__global__ void k_convert_x(const float* __restrict__ x, unsigned char* __restrict__ xq) {
    int i = (blockIdx.x * blockDim.x + threadIdx.x) * 4;
    float4 v = *(const float4*)(x + i);
    uint32_t o = (uint32_t)q8(v.x, XSCALE)
               | ((uint32_t)q8(v.y, XSCALE) << 8)
               | ((uint32_t)q8(v.z, XSCALE) << 16)
               | ((uint32_t)q8(v.w, XSCALE) << 24);
    *(uint32_t*)(xq + i) = o;
}

// ---- K2: W [H][V] fp32 -> Wq [V][H] i8 (scale 512), tiled transpose --------
__global__ void k_transpose_w(const float* __restrict__ W, unsigned char* __restrict__ wq) {
    __shared__ unsigned char tile[32][36];
    int v0 = blockIdx.x * 32;
    int k0 = blockIdx.y * 32;
    int tx = threadIdx.x;   // 0..7  (k-quad on store, v-quad on load)
    int ty = threadIdx.y;   // 0..31
    // load: k = k0+ty, v = v0 + tx*4 .. +3
    float4 v = *(const float4*)(W + (size_t)(k0 + ty) * V_SIZE + v0 + tx * 4);
    tile[ty][tx * 4 + 0] = (unsigned char)q8(v.x, WSCALE);
    tile[ty][tx * 4 + 1] = (unsigned char)q8(v.y, WSCALE);
    tile[ty][tx * 4 + 2] = (unsigned char)q8(v.z, WSCALE);
    tile[ty][tx * 4 + 3] = (unsigned char)q8(v.w, WSCALE);
    __syncthreads();
    // store: v = v0+ty, k = k0 + tx*4 .. +3
    uint32_t o = (uint32_t)tile[tx * 4 + 0][ty]
               | ((uint32_t)tile[tx * 4 + 1][ty] << 8)
               | ((uint32_t)tile[tx * 4 + 2][ty] << 16)
               | ((uint32_t)tile[tx * 4 + 3][ty] << 24);
    *(uint32_t*)(wq + (size_t)(v0 + ty) * H_DIM + k0 + tx * 4) = o;
}

// ---- K3: fused i8 GEMM (Wq x xq^T) + exp + column-sum partials -------------
// logits[v][n] = (sum_k Wq[v][k]*xq[n][k]) * DESCALE
// Spart[vt][n] = sum_{v in tile} exp(logit)
// Identical byte geometry / swizzle to the proven bf16 round-1 kernel:
// 128 rows x 128B LDS tiles, 8 16B-slots per row, slot ^= (row&7).
__global__ __launch_bounds__(256, 2) void k_gemm_expsum(
    const unsigned char* __restrict__ wq,
    const unsigned char* __restrict__ xq,
    float* __restrict__ Spart)
{
    __shared__ __align__(16) unsigned char a_sm[BV * BKB];
    __shared__ __align__(16) unsigned char b_sm[BN * BKB];
    __shared__ float red[2][BN];

    const int bid = blockIdx.x;
    const int nt = bid & (N_TILES - 1);
    const int vt = bid >> 5;
    const int v0 = vt * BV;
    const int n0 = nt * BN;

    const int t = threadIdx.x;
    const int lane = t & 63;
    const int w = t >> 6;       // wave 0..3
    const int wv = w >> 1;      // v half
    const int wn = w & 1;       // n half

    const int srcColb = (((lane & 7) ^ (lane >> 3)) << 4);
    const unsigned char* aG = wq + (size_t)v0 * H_DIM;
    const unsigned char* bG = xq + (size_t)n0 * H_DIM;

    intx4 acc[4][4] = {};

    for (int kt = 0; kt < K_TILES; ++kt) {
        const size_t kb = (size_t)kt * BKB;
#pragma unroll
        for (int c = 0; c < 4; ++c) {
            int row = w * 32 + c * 8 + (lane >> 3);
            gload_lds16(aG + (size_t)row * H_DIM + kb + srcColb,
                        (unsigned char*)a_sm + (w * 4 + c) * 1024);
        }
#pragma unroll
        for (int c = 0; c < 4; ++c) {
            int row = w * 32 + c * 8 + (lane >> 3);
            gload_lds16(bG + (size_t)row * H_DIM + kb + srcColb,
                        (unsigned char*)b_sm + (w * 4 + c) * 1024);
        }
        asm volatile("s_waitcnt vmcnt(0)" ::: "memory");
        __syncthreads();

#pragma unroll
        for (int ks = 0; ks < 2; ++ks) {
            const int koff = ks * 64 + ((lane >> 4) << 4);
            intx4 af[4], bfr[4];
#pragma unroll
            for (int m = 0; m < 4; ++m) {
                int vr = wv * 64 + m * 16 + (lane & 15);
                int addr = vr * 128 + (koff ^ ((vr & 7) << 4));
                af[m] = *(const intx4*)((const unsigned char*)a_sm + addr);
            }
#pragma unroll
            for (int n = 0; n < 4; ++n) {
                int nr = wn * 64 + n * 16 + (lane & 15);
                int addr = nr * 128 + (koff ^ ((nr & 7) << 4));
                bfr[n] = *(const intx4*)((const unsigned char*)b_sm + addr);
            }
#pragma unroll
            for (int m = 0; m < 4; ++m)
#pragma unroll
                for (int n = 0; n < 4; ++n)
                    acc[m][n] = __builtin_amdgcn_mfma_i32_16x16x64_i8(
                        af[m], bfr[n], acc[m][n], 0, 0, 0);
        }
        __syncthreads();
    }

    // epilogue: descale + exp + column sums. C/D: col=lane&15 (n), row=(lane>>4)*4+r (v)
    float csum[4];
#pragma unroll
    for (int nf = 0; nf < 4; ++nf) {
        float s = 0.f;
#pragma unroll
        for (int m = 0; m < 4; ++m)
#pragma unroll
            for (int r = 0; r < 4; ++r)
                s += __expf((float)acc[m][nf][r] * DESCALE);
        s += __shfl_xor(s, 16, 64);
        s += __shfl_xor(s, 32, 64);
        csum[nf] = s;
    }
    if ((lane >> 4) == 0) {
#pragma unroll
        for (int nf = 0; nf < 4; ++nf)
            red[wv][wn * 64 + nf * 16 + lane] = csum[nf];
    }
    __syncthreads();
    if (t < BN) {
        float S = red[0][t] + red[1][t];
        Spart[(size_t)vt * N_ROWS + n0 + t] = S;
    }
}

// ---- K4: target logits (same quantized values -> consistent numerics) ------
__global__ void k_tgt(const unsigned char* __restrict__ xq,
                      const unsigned char* __restrict__ wq,
                      const int* __restrict__ tgt,
                      float* __restrict__ tlog)
{
    int w = threadIdx.x >> 6;
    int lane = threadIdx.x & 63;
    int n = blockIdx.x * 4 + w;
    int tg = tgt[n];
    int ts = (tg == IGNORE_INDEX) ? 0 : tg;
    const unsigned char* xr = xq + (size_t)n * H_DIM;
    const unsigned char* wr = wq + (size_t)ts * H_DIM;
    int s = 0;
#pragma unroll
    for (int i = 0; i < 4; ++i) {
        uint32_t xa = *(const uint32_t*)(xr + lane * 4 + i * 256);
        uint32_t wa = *(const uint32_t*)(wr + lane * 4 + i * 256);
#pragma unroll
        for (int j = 0; j < 4; ++j) {
            int xe = (int)(int8_t)((xa >> (8 * j)) & 0xff);
            int we = (int)(int8_t)((wa >> (8 * j)) & 0xff);
            s += xe * we;
        }
    }
#pragma unroll
    for (int off = 32; off; off >>= 1) s += __shfl_xor(s, off, 64);
    if (lane == 0) tlog[n] = (float)s * DESCALE;
}

// ---- K5: per-row loss + block partials -------------------------------------
__global__ void k_rowloss(const float* __restrict__ Spart,
                          const float* __restrict__ tlog,
                          const int* __restrict__ tgt,
                          float* __restrict__ partials)
{
    int n = blockIdx.x * 256 + threadIdx.x;
    float S = 0.f;
    for (int vt2 = 0; vt2 < V_TILES; ++vt2)
        S += Spart[(size_t)vt2 * N_ROWS + n];
    float loss = 0.f;
    int tg = tgt[n];
    if (tg != IGNORE_INDEX) loss = logf(S) - tlog[n];

    __shared__ float sm[256];
    sm[threadIdx.x] = loss;
    __syncthreads();
    for (int s2 = 128; s2 > 0; s2 >>= 1) {
        if (threadIdx.x < s2) sm[threadIdx.x] += sm[threadIdx.x + s2];
        __syncthreads();
    }
    if (threadIdx.x == 0) partials[blockIdx.x] = sm[0];
}

__global__ void k_final(const float* __restrict__ partials, float* __restrict__ out) {
    if (threadIdx.x == 0) {
        float s = 0.f;
        for (int i = 0; i < 16; ++i) s += partials[i];
        out[0] = s;
    }
}

// ---- launch ----------------------------------------------------------------
extern "C" void kernel_launch(void* const* d_in, const int* in_sizes, int n_in,
                              void* d_out, int out_size, void* d_ws, size_t ws_size,
                              hipStream_t stream)
{
    const float* x = (const float*)d_in[0];
    const float* W = (const float*)d_in[1];
    const int* tgt = (const int*)d_in[2];
    float* out = (float*)d_out;

    char* ws = (char*)d_ws;
    size_t off = 0;
    unsigned char* xq = (unsigned char*)(ws + off); off += (size_t)N_ROWS * H_DIM;
    unsigned char* wq = (unsigned char*)(ws + off); off += (size_t)V_SIZE * H_DIM;
    float* Spart = (float*)(ws + off);              off += (size_t)V_TILES * N_ROWS * 4;
    float* tlog  = (float*)(ws + off);              off += (size_t)N_ROWS * 4;
    float* partials = (float*)(ws + off);           off += 64;

    k_convert_x<<<(N_ROWS * H_DIM / 4) / 256, 256, 0, stream>>>(x, xq);
    k_transpose_w<<<dim3(V_SIZE / 32, H_DIM / 32), dim3(8, 32), 0, stream>>>(W, wq);
    k_gemm_expsum<<<V_TILES * N_TILES, 256, 0, stream>>>(wq, xq, Spart);
    k_tgt<<<N_ROWS / 4, 256, 0, stream>>>(xq, wq, tgt, tlog);
    k_rowloss<<<16, 256, 0, stream>>>(Spart, tlog, tgt, partials);
    k_final<<<1, 64, 0, stream>>>(partials, out);
}